// Round 7
// baseline (104.031 us; speedup 1.0000x reference)
//
#include <hip/hip_runtime.h>
#include <hip/hip_bf16.h>
#include <cstdint>

#define N_PTS 16384
#define DIM   64
#define BM    128          // rows per block
#define CHUNK 1024         // cols per block  (R7: single change vs R6, 2048->1024)
#define NT    (CHUNK / 64) // 16 col-tiles of 64 per block
#define NPANEL (N_PTS / BM)    // 128
#define NCHUNK (N_PTS / CHUNK) // 16

typedef __attribute__((ext_vector_type(8))) short short8;
typedef __attribute__((ext_vector_type(4))) float f32x4;

// ---- workspace layout (bytes) ----
#define A_BF_OFF  0u
#define B_BF_OFF  ((unsigned)(N_PTS * DIM * 2))                 // 2 MB
#define A2_OFF    ((unsigned)(2u * N_PTS * DIM * 2))            // 4 MB
#define B2_OFF    (A2_OFF + (unsigned)(N_PTS * 4))
#define ROW_OFF   (B2_OFF + (unsigned)(N_PTS * 4))              // [NCHUNK][N_PTS] f32
#define COL_OFF   (ROW_OFF + (unsigned)(NCHUNK * N_PTS * 4))    // [NPANEL][N_PTS] f32
#define PART_OFF  (COL_OFF + (unsigned)(NPANEL * N_PTS * 4))    // [64] f32

__device__ __forceinline__ unsigned f2o(float f) {
    unsigned b = __float_as_uint(f);
    return b ^ (unsigned)((((int)b) >> 31) | 0x80000000);
}
__device__ __forceinline__ float o2f(unsigned u) {
    unsigned b = (u & 0x80000000u) ? (u ^ 0x80000000u) : ~u;
    return __uint_as_float(b);
}
__device__ __forceinline__ unsigned short f2bf(float f) {
    unsigned b = __float_as_uint(f);
    b += 0x7FFFu + ((b >> 16) & 1u);
    return (unsigned short)(b >> 16);
}
__device__ __forceinline__ float min3f(float a, float b, float c) {
    return fminf(fminf(a, b), c);   // clang fuses to v_min3_f32
}

// ---------------- convert + norms + k-group-major transpose ----------------
// X'[kg][16384 rows][8 bf16], kg = k/8.  A side scaled by -2 (exact in bf16).
__global__ __launch_bounds__(256) void cd_convert(
    const float* __restrict__ a, const float* __restrict__ b,
    unsigned short* __restrict__ abf, unsigned short* __restrict__ bbf,
    float* __restrict__ a2, float* __restrict__ b2) {
    __shared__ ushort4 T[16][17];
    const int blk = blockIdx.x;                 // 0..2047
    const bool isB = blk >= (N_PTS / 16);
    const float* src = isB ? b : a;
    unsigned short* dst = isB ? bbf : abf;
    float* nrm = isB ? b2 : a2;
    const int rb = (blk & (N_PTS / 16 - 1)) * 16;
    const int tid = threadIdx.x;

    {
        int rowl = tid >> 4, part = tid & 15;
        float4 v = ((const float4*)src)[(size_t)(rb + rowl) * 16 + part];
        float s = v.x * v.x + v.y * v.y + v.z * v.z + v.w * v.w;
        s += __shfl_xor(s, 1, 64);
        s += __shfl_xor(s, 2, 64);
        s += __shfl_xor(s, 4, 64);
        s += __shfl_xor(s, 8, 64);
        if (part == 0) nrm[rb + rowl] = s;
        float sc = isB ? 1.0f : -2.0f;
        ushort4 u;
        u.x = f2bf(sc * v.x); u.y = f2bf(sc * v.y);
        u.z = f2bf(sc * v.z); u.w = f2bf(sc * v.w);
        T[rowl][part] = u;
    }
    __syncthreads();
    {
        int kgh = tid >> 4, rl = tid & 15;
        ushort4 w = T[rl][kgh];
        int kg = kgh >> 1, half = kgh & 1;
        ((ushort4*)dst)[(size_t)(kg * N_PTS + rb + rl) * 2 + half] = w;
    }
}

// ---------------- fused GEMM + min epilogue ----------------
// R2's verified loop schedule (loadB(t+1); compute(t); loadB(t+2); compute(t+1))
// with compute = ONE fused mfma+epilogue section.  MFMA C-init = a2 fragment
// (acc = a2 - 2ab), min3 trees, b2 deferred on the col path (added in
// cd_reduce).  R7: CHUNK=1024 -> 2048 blocks, 8 blocks/CU for tail/residency.
__global__ __launch_bounds__(256, 3) void cd_gemm(
    const unsigned short* __restrict__ abf, const unsigned short* __restrict__ bbf,
    const float* __restrict__ a2, const float* __restrict__ b2,
    float* __restrict__ ws_row, float* __restrict__ ws_col) {

    __shared__ unsigned colmin[CHUNK];     // 4 KB
    __shared__ unsigned rowmin_s[BM];      // 512 B

    const int tid  = threadIdx.x;
    const int lane = tid & 63;
    const int wid  = tid >> 6;
    const int wm   = wid >> 1;
    const int wn   = wid & 1;
    const int l15  = lane & 15;
    const int l4   = lane >> 4;
    const int cblk = blockIdx.x;
    const int pblk = blockIdx.y;
    const int rowbase = pblk * BM;
    const int colbase = cblk * CHUNK;

    for (int i = tid; i < CHUNK; i += 256) colmin[i] = 0xFFFFFFFFu;
    if (tid < BM) rowmin_s[tid] = 0xFFFFFFFFu;

    // A fragments + a2 fragments direct to registers (k-group-major layout)
    short8 af[2][4];
    #pragma unroll
    for (int ks = 0; ks < 2; ++ks)
        #pragma unroll
        for (int m = 0; m < 4; ++m) {
            int arow = rowbase + wm * 64 + m * 16 + l15;
            af[ks][m] = *(const short8*)(abf + (size_t)((ks * 4 + l4) * N_PTS + arow) * 8);
        }
    f32x4 a2v[4];
    #pragma unroll
    for (int m = 0; m < 4; ++m)
        a2v[m] = *(const f32x4*)(a2 + rowbase + wm * 64 + m * 16 + l4 * 4);

    float rowm[16];
    #pragma unroll
    for (int i = 0; i < 16; ++i) rowm[i] = __builtin_inff();

    __syncthreads();   // colmin init visible before any atomicMin

    auto loadB = [&](int t, short8 (&bf)[2][2], float (&bv)[2]) {
        int col0 = colbase + t * 64 + wn * 32;
        #pragma unroll
        for (int n = 0; n < 2; ++n) {
            int col = col0 + n * 16 + l15;
            #pragma unroll
            for (int ks = 0; ks < 2; ++ks)
                bf[ks][n] = *(const short8*)(bbf + (size_t)((ks * 4 + l4) * N_PTS + col) * 8);
            bv[n] = b2[col];
        }
    };

    // ONE fused section per tile (R2-proven schedule).
    auto compute = [&](int t, const short8 (&bf)[2][2], const float (&bv)[2]) {
        f32x4 acc[4][2];
        #pragma unroll
        for (int m = 0; m < 4; ++m)
            #pragma unroll
            for (int n = 0; n < 2; ++n)
                acc[m][n] = __builtin_amdgcn_mfma_f32_16x16x32_bf16(af[0][m], bf[0][n], a2v[m], 0, 0, 0);
        #pragma unroll
        for (int m = 0; m < 4; ++m)
            #pragma unroll
            for (int n = 0; n < 2; ++n)
                acc[m][n] = __builtin_amdgcn_mfma_f32_16x16x32_bf16(af[1][m], bf[1][n], acc[m][n], 0, 0, 0);

        // col tree on raw acc (b2 deferred to cd_reduce)
        float colt[2] = {__builtin_inff(), __builtin_inff()};
        #pragma unroll
        for (int n = 0; n < 2; ++n)
            #pragma unroll
            for (int m = 0; m < 4; ++m) {
                colt[n] = min3f(colt[n], acc[m][n][0], acc[m][n][1]);
                colt[n] = min3f(colt[n], acc[m][n][2], acc[m][n][3]);
            }
        // row tree on acc + b2
        #pragma unroll
        for (int m = 0; m < 4; ++m)
            #pragma unroll
            for (int r = 0; r < 4; ++r)
                rowm[m * 4 + r] = min3f(rowm[m * 4 + r],
                                        acc[m][0][r] + bv[0],
                                        acc[m][1][r] + bv[1]);
        // col cross-lane: shfl over lane bits 4,5; one guarded atomic
        #pragma unroll
        for (int n = 0; n < 2; ++n) {
            float v = fminf(colt[n], __shfl_xor(colt[n], 16, 64));
            v = fminf(v, __shfl_xor(v, 32, 64));
            if (lane < 16)
                atomicMin(&colmin[t * 64 + wn * 32 + n * 16 + lane], f2o(v));
        }
    };

    short8 bfA[2][2], bfB[2][2];
    float bvA[2], bvB[2];
    loadB(0, bfA, bvA);
    for (int t = 0; t < NT; t += 2) {
        loadB(t + 1, bfB, bvB);        // prefetch next while computing current
        compute(t, bfA, bvA);
        if (t + 2 < NT) loadB(t + 2, bfA, bvA);
        compute(t + 1, bfB, bvB);
    }

    // row mins: reduce over l15 lanes, combine across wn via LDS
    #pragma unroll
    for (int i = 0; i < 16; ++i) {
        float v = rowm[i];
        v = fminf(v, __shfl_xor(v, 1, 64));
        v = fminf(v, __shfl_xor(v, 2, 64));
        v = fminf(v, __shfl_xor(v, 4, 64));
        v = fminf(v, __shfl_xor(v, 8, 64));
        if (l15 == 0)
            atomicMin(&rowmin_s[wm * 64 + (i >> 2) * 16 + l4 * 4 + (i & 3)], f2o(v));
    }
    __syncthreads();

    if (tid < BM)
        ws_row[(size_t)cblk * N_PTS + rowbase + tid] = o2f(rowmin_s[tid]);
    for (int i = tid; i < CHUNK; i += 256)
        ws_col[(size_t)pblk * N_PTS + colbase + i] = o2f(colmin[i]);
}

// ---------------- final reduction ----------------
__global__ __launch_bounds__(256) void cd_reduce(
    const float* __restrict__ ws_row, const float* __restrict__ ws_col,
    const float* __restrict__ b2, float* __restrict__ partial) {
    int i = blockIdx.x * 256 + threadIdx.x;    // 0..16383
    float rm = __builtin_inff(), cm = __builtin_inff();
    #pragma unroll 4
    for (int c = 0; c < NCHUNK; ++c) rm = fminf(rm, ws_row[(size_t)c * N_PTS + i]);
    #pragma unroll 4
    for (int p = 0; p < NPANEL; ++p) cm = fminf(cm, ws_col[(size_t)p * N_PTS + i]);
    float cmf = cm + b2[i];                    // deferred b2 for the col path
    float s = sqrtf(fmaxf(rm, 0.f)) + sqrtf(fmaxf(cmf, 0.f));
    s += __shfl_xor(s, 1, 64);
    s += __shfl_xor(s, 2, 64);
    s += __shfl_xor(s, 4, 64);
    s += __shfl_xor(s, 8, 64);
    s += __shfl_xor(s, 16, 64);
    s += __shfl_xor(s, 32, 64);
    __shared__ float wsum[4];
    if ((threadIdx.x & 63) == 0) wsum[threadIdx.x >> 6] = s;
    __syncthreads();
    if (threadIdx.x == 0)
        partial[blockIdx.x] = wsum[0] + wsum[1] + wsum[2] + wsum[3];
}

__global__ void cd_final(const float* __restrict__ partial, float* __restrict__ out) {
    float s = partial[threadIdx.x];   // 64 entries
    s += __shfl_xor(s, 1, 64);
    s += __shfl_xor(s, 2, 64);
    s += __shfl_xor(s, 4, 64);
    s += __shfl_xor(s, 8, 64);
    s += __shfl_xor(s, 16, 64);
    s += __shfl_xor(s, 32, 64);
    if (threadIdx.x == 0) out[0] = s * (1.0f / (2.0f * N_PTS));
}

extern "C" void kernel_launch(void* const* d_in, const int* in_sizes, int n_in,
                              void* d_out, int out_size, void* d_ws, size_t ws_size,
                              hipStream_t stream) {
    const float* a = (const float*)d_in[0];
    const float* b = (const float*)d_in[1];
    char* ws = (char*)d_ws;
    unsigned short* abf = (unsigned short*)(ws + A_BF_OFF);
    unsigned short* bbf = (unsigned short*)(ws + B_BF_OFF);
    float* a2     = (float*)(ws + A2_OFF);
    float* b2     = (float*)(ws + B2_OFF);
    float* ws_row = (float*)(ws + ROW_OFF);
    float* ws_col = (float*)(ws + COL_OFF);
    float* part   = (float*)(ws + PART_OFF);

    cd_convert<<<dim3(2 * N_PTS / 16), 256, 0, stream>>>(a, b, abf, bbf, a2, b2);
    cd_gemm<<<dim3(NCHUNK, NPANEL), 256, 0, stream>>>(abf, bbf, a2, b2, ws_row, ws_col);
    cd_reduce<<<dim3(N_PTS / 256), 256, 0, stream>>>(ws_row, ws_col, b2, part);
    cd_final<<<1, 64, 0, stream>>>(part, (float*)d_out);
}

// Round 8
// 75.207 us; speedup vs baseline: 1.3833x; 1.3833x over previous
//
#include <hip/hip_runtime.h>
#include <hip/hip_bf16.h>
#include <cstdint>

#define N_PTS 16384
#define DIM   64
#define BM    128          // rows per block
#define CHUNK 2048         // cols per block (R6 best-measured config)
#define NT    (CHUNK / 64) // 32 col-tiles of 64 per block
#define NPANEL (N_PTS / BM)    // 128
#define NCHUNK (N_PTS / CHUNK) // 8

typedef __attribute__((ext_vector_type(8))) short short8;
typedef __attribute__((ext_vector_type(4))) float f32x4;

// ---- workspace layout (bytes) ----
#define A_BF_OFF  0u
#define B_BF_OFF  ((unsigned)(N_PTS * DIM * 2))                 // 2 MB
#define A2_OFF    ((unsigned)(2u * N_PTS * DIM * 2))            // 4 MB
#define B2_OFF    (A2_OFF + (unsigned)(N_PTS * 4))
#define ROW_OFF   (B2_OFF + (unsigned)(N_PTS * 4))              // [NCHUNK][N_PTS] f32
#define COL_OFF   (ROW_OFF + (unsigned)(NCHUNK * N_PTS * 4))    // [NPANEL][N_PTS] f32
#define PART_OFF  (COL_OFF + (unsigned)(NPANEL * N_PTS * 4))    // [64] f32

__device__ __forceinline__ unsigned f2o(float f) {
    unsigned b = __float_as_uint(f);
    return b ^ (unsigned)((((int)b) >> 31) | 0x80000000);
}
__device__ __forceinline__ float o2f(unsigned u) {
    unsigned b = (u & 0x80000000u) ? (u ^ 0x80000000u) : ~u;
    return __uint_as_float(b);
}
__device__ __forceinline__ unsigned short f2bf(float f) {
    unsigned b = __float_as_uint(f);
    b += 0x7FFFu + ((b >> 16) & 1u);
    return (unsigned short)(b >> 16);
}
__device__ __forceinline__ float min3f(float a, float b, float c) {
    return fminf(fminf(a, b), c);   // clang fuses to v_min3_f32
}

// ---------------- convert + norms + k-group-major transpose ----------------
// X'[kg][16384 rows][8 bf16], kg = k/8.  A side scaled by -2 (exact in bf16).
__global__ __launch_bounds__(256) void cd_convert(
    const float* __restrict__ a, const float* __restrict__ b,
    unsigned short* __restrict__ abf, unsigned short* __restrict__ bbf,
    float* __restrict__ a2, float* __restrict__ b2) {
    __shared__ ushort4 T[16][17];
    const int blk = blockIdx.x;                 // 0..2047
    const bool isB = blk >= (N_PTS / 16);
    const float* src = isB ? b : a;
    unsigned short* dst = isB ? bbf : abf;
    float* nrm = isB ? b2 : a2;
    const int rb = (blk & (N_PTS / 16 - 1)) * 16;
    const int tid = threadIdx.x;

    {
        int rowl = tid >> 4, part = tid & 15;
        float4 v = ((const float4*)src)[(size_t)(rb + rowl) * 16 + part];
        float s = v.x * v.x + v.y * v.y + v.z * v.z + v.w * v.w;
        s += __shfl_xor(s, 1, 64);
        s += __shfl_xor(s, 2, 64);
        s += __shfl_xor(s, 4, 64);
        s += __shfl_xor(s, 8, 64);
        if (part == 0) nrm[rb + rowl] = s;
        float sc = isB ? 1.0f : -2.0f;
        ushort4 u;
        u.x = f2bf(sc * v.x); u.y = f2bf(sc * v.y);
        u.z = f2bf(sc * v.z); u.w = f2bf(sc * v.w);
        T[rowl][part] = u;
    }
    __syncthreads();
    {
        int kgh = tid >> 4, rl = tid & 15;
        ushort4 w = T[rl][kgh];
        int kg = kgh >> 1, half = kgh & 1;
        ((ushort4*)dst)[(size_t)(kg * N_PTS + rb + rl) * 2 + half] = w;
    }
}

// ---------------- fused GEMM + min epilogue ----------------
// R2's verified loop schedule (loadB(t+1); compute(t); loadB(t+2); compute(t+1))
// with compute = ONE fused mfma+epilogue section.  MFMA C-init = a2 fragment
// (acc = a2 - 2ab), min3 trees, b2 deferred on the col path.
// R8 single change vs R6: col-min cross-lane shfl chain (lgkmcnt wave-stall
// every tile) replaced by all-64-lane no-return LDS atomicMin (4-way
// same-address dup ~0.85us chip-wide, zero wave-stall).  Main loop now has
// NO DS-read/shfl waits at all -- only prefetched-load vmcnt.
__global__ __launch_bounds__(256, 3) void cd_gemm(
    const unsigned short* __restrict__ abf, const unsigned short* __restrict__ bbf,
    const float* __restrict__ a2, const float* __restrict__ b2,
    float* __restrict__ ws_row, float* __restrict__ ws_col) {

    __shared__ unsigned colmin[CHUNK];     // 8 KB
    __shared__ unsigned rowmin_s[BM];      // 512 B

    const int tid  = threadIdx.x;
    const int lane = tid & 63;
    const int wid  = tid >> 6;
    const int wm   = wid >> 1;
    const int wn   = wid & 1;
    const int l15  = lane & 15;
    const int l4   = lane >> 4;
    const int cblk = blockIdx.x;
    const int pblk = blockIdx.y;
    const int rowbase = pblk * BM;
    const int colbase = cblk * CHUNK;

    for (int i = tid; i < CHUNK; i += 256) colmin[i] = 0xFFFFFFFFu;
    if (tid < BM) rowmin_s[tid] = 0xFFFFFFFFu;

    // A fragments + a2 fragments direct to registers (k-group-major layout)
    short8 af[2][4];
    #pragma unroll
    for (int ks = 0; ks < 2; ++ks)
        #pragma unroll
        for (int m = 0; m < 4; ++m) {
            int arow = rowbase + wm * 64 + m * 16 + l15;
            af[ks][m] = *(const short8*)(abf + (size_t)((ks * 4 + l4) * N_PTS + arow) * 8);
        }
    f32x4 a2v[4];
    #pragma unroll
    for (int m = 0; m < 4; ++m)
        a2v[m] = *(const f32x4*)(a2 + rowbase + wm * 64 + m * 16 + l4 * 4);

    float rowm[16];
    #pragma unroll
    for (int i = 0; i < 16; ++i) rowm[i] = __builtin_inff();

    __syncthreads();   // colmin init visible before any atomicMin

    auto loadB = [&](int t, short8 (&bf)[2][2], float (&bv)[2]) {
        int col0 = colbase + t * 64 + wn * 32;
        #pragma unroll
        for (int n = 0; n < 2; ++n) {
            int col = col0 + n * 16 + l15;
            #pragma unroll
            for (int ks = 0; ks < 2; ++ks)
                bf[ks][n] = *(const short8*)(bbf + (size_t)((ks * 4 + l4) * N_PTS + col) * 8);
            bv[n] = b2[col];
        }
    };

    // ONE fused section per tile (R2-proven schedule).
    auto compute = [&](int t, const short8 (&bf)[2][2], const float (&bv)[2]) {
        f32x4 acc[4][2];
        #pragma unroll
        for (int m = 0; m < 4; ++m)
            #pragma unroll
            for (int n = 0; n < 2; ++n)
                acc[m][n] = __builtin_amdgcn_mfma_f32_16x16x32_bf16(af[0][m], bf[0][n], a2v[m], 0, 0, 0);
        #pragma unroll
        for (int m = 0; m < 4; ++m)
            #pragma unroll
            for (int n = 0; n < 2; ++n)
                acc[m][n] = __builtin_amdgcn_mfma_f32_16x16x32_bf16(af[1][m], bf[1][n], acc[m][n], 0, 0, 0);

        // col tree on raw acc (b2 deferred to cd_reduce)
        float colt[2] = {__builtin_inff(), __builtin_inff()};
        #pragma unroll
        for (int n = 0; n < 2; ++n)
            #pragma unroll
            for (int m = 0; m < 4; ++m) {
                colt[n] = min3f(colt[n], acc[m][n][0], acc[m][n][1]);
                colt[n] = min3f(colt[n], acc[m][n][2], acc[m][n][3]);
            }
        // row tree on acc + b2
        #pragma unroll
        for (int m = 0; m < 4; ++m)
            #pragma unroll
            for (int r = 0; r < 4; ++r)
                rowm[m * 4 + r] = min3f(rowm[m * 4 + r],
                                        acc[m][0][r] + bv[0],
                                        acc[m][1][r] + bv[1]);
        // col cross-lane: all 64 lanes fire-and-forget ds atomic (no return,
        // no lgkmcnt wait in-loop; l4 groups dup 4-way on the same address)
        #pragma unroll
        for (int n = 0; n < 2; ++n)
            atomicMin(&colmin[t * 64 + wn * 32 + n * 16 + l15], f2o(colt[n]));
    };

    short8 bfA[2][2], bfB[2][2];
    float bvA[2], bvB[2];
    loadB(0, bfA, bvA);
    for (int t = 0; t < NT; t += 2) {
        loadB(t + 1, bfB, bvB);        // prefetch next while computing current
        compute(t, bfA, bvA);
        if (t + 2 < NT) loadB(t + 2, bfA, bvA);
        compute(t + 1, bfB, bvB);
    }

    // row mins: reduce over l15 lanes, combine across wn via LDS (once/block)
    #pragma unroll
    for (int i = 0; i < 16; ++i) {
        float v = rowm[i];
        v = fminf(v, __shfl_xor(v, 1, 64));
        v = fminf(v, __shfl_xor(v, 2, 64));
        v = fminf(v, __shfl_xor(v, 4, 64));
        v = fminf(v, __shfl_xor(v, 8, 64));
        if (l15 == 0)
            atomicMin(&rowmin_s[wm * 64 + (i >> 2) * 16 + l4 * 4 + (i & 3)], f2o(v));
    }
    __syncthreads();

    if (tid < BM)
        ws_row[(size_t)cblk * N_PTS + rowbase + tid] = o2f(rowmin_s[tid]);
    for (int i = tid; i < CHUNK; i += 256)
        ws_col[(size_t)pblk * N_PTS + colbase + i] = o2f(colmin[i]);
}

// ---------------- final reduction ----------------
__global__ __launch_bounds__(256) void cd_reduce(
    const float* __restrict__ ws_row, const float* __restrict__ ws_col,
    const float* __restrict__ b2, float* __restrict__ partial) {
    int i = blockIdx.x * 256 + threadIdx.x;    // 0..16383
    float rm = __builtin_inff(), cm = __builtin_inff();
    #pragma unroll 4
    for (int c = 0; c < NCHUNK; ++c) rm = fminf(rm, ws_row[(size_t)c * N_PTS + i]);
    #pragma unroll 4
    for (int p = 0; p < NPANEL; ++p) cm = fminf(cm, ws_col[(size_t)p * N_PTS + i]);
    float cmf = cm + b2[i];                    // deferred b2 for the col path
    float s = sqrtf(fmaxf(rm, 0.f)) + sqrtf(fmaxf(cmf, 0.f));
    s += __shfl_xor(s, 1, 64);
    s += __shfl_xor(s, 2, 64);
    s += __shfl_xor(s, 4, 64);
    s += __shfl_xor(s, 8, 64);
    s += __shfl_xor(s, 16, 64);
    s += __shfl_xor(s, 32, 64);
    __shared__ float wsum[4];
    if ((threadIdx.x & 63) == 0) wsum[threadIdx.x >> 6] = s;
    __syncthreads();
    if (threadIdx.x == 0)
        partial[blockIdx.x] = wsum[0] + wsum[1] + wsum[2] + wsum[3];
}

__global__ void cd_final(const float* __restrict__ partial, float* __restrict__ out) {
    float s = partial[threadIdx.x];   // 64 entries
    s += __shfl_xor(s, 1, 64);
    s += __shfl_xor(s, 2, 64);
    s += __shfl_xor(s, 4, 64);
    s += __shfl_xor(s, 8, 64);
    s += __shfl_xor(s, 16, 64);
    s += __shfl_xor(s, 32, 64);
    if (threadIdx.x == 0) out[0] = s * (1.0f / (2.0f * N_PTS));
}

extern "C" void kernel_launch(void* const* d_in, const int* in_sizes, int n_in,
                              void* d_out, int out_size, void* d_ws, size_t ws_size,
                              hipStream_t stream) {
    const float* a = (const float*)d_in[0];
    const float* b = (const float*)d_in[1];
    char* ws = (char*)d_ws;
    unsigned short* abf = (unsigned short*)(ws + A_BF_OFF);
    unsigned short* bbf = (unsigned short*)(ws + B_BF_OFF);
    float* a2     = (float*)(ws + A2_OFF);
    float* b2     = (float*)(ws + B2_OFF);
    float* ws_row = (float*)(ws + ROW_OFF);
    float* ws_col = (float*)(ws + COL_OFF);
    float* part   = (float*)(ws + PART_OFF);

    cd_convert<<<dim3(2 * N_PTS / 16), 256, 0, stream>>>(a, b, abf, bbf, a2, b2);
    cd_gemm<<<dim3(NCHUNK, NPANEL), 256, 0, stream>>>(abf, bbf, a2, b2, ws_row, ws_col);
    cd_reduce<<<dim3(N_PTS / 256), 256, 0, stream>>>(ws_row, ws_col, b2, part);
    cd_final<<<1, 64, 0, stream>>>(part, (float*)d_out);
}